// Round 10
// baseline (152.601 us; speedup 1.0000x reference)
//
#include <hip/hip_runtime.h>

#define AS1 __attribute__((address_space(1)))
#define AS3 __attribute__((address_space(3)))

typedef __bf16 bf16x8 __attribute__((ext_vector_type(8)));
typedef float f32x4 __attribute__((ext_vector_type(4)));
typedef float f32x16 __attribute__((ext_vector_type(16)));
typedef unsigned short ushort8 __attribute__((ext_vector_type(8)));

// round-to-nearest-even f32 -> bf16
__device__ __forceinline__ unsigned short f2bf(float f) {
  union { float f; unsigned u; } v; v.f = f;
  unsigned u = v.u;
  unsigned r = (u + 0x7fffu + ((u >> 16) & 1u)) >> 16;
  return (unsigned short)r;
}

// ---------------------------------------------------------------------------
// prepx: merged prep (blocks 0..127) + xconv (blocks 128..2175).
// prep: reads each W element once -> partial[is][b][o] (32-batch FMA chains)
//       + WT[o][i] bf16 transpose. xconv: X = bf16(Efou * ys).
// ---------------------------------------------------------------------------
__global__ __launch_bounds__(256) void prepx_kernel(
    const float* __restrict__ y, const float* __restrict__ W,
    const float4* __restrict__ E4, float* __restrict__ partial,
    unsigned short* __restrict__ WT, unsigned short* __restrict__ X) {
  __shared__ float ysq[32][32];  // [i_local][b] (prep half only)
  const int bid = blockIdx.x;
  if (bid < 128) {
    // ---- prep ----
    const int o = (bid & 3) * 256 + threadIdx.x;
    const int i0 = (bid >> 2) * 32;
    for (int e = threadIdx.x; e < 1024; e += 256) {
      int il = e >> 5, b = e & 31;
      float t = y[b * 1024 + i0 + il] * 0.03125f;
      ysq[il][b] = t * t;
    }
    __syncthreads();

    f32x4 acc[8] = {};
    ushort8 wb[4];
#pragma unroll
    for (int il = 0; il < 32; ++il) {
      float w = W[(size_t)(i0 + il) * 1024 + o];
      wb[il >> 3][il & 7] = f2bf(w);
      float w2 = w * w;
#pragma unroll
      for (int b4 = 0; b4 < 8; ++b4) {
        f32x4 q = *(const f32x4*)&ysq[il][b4 * 4];
#pragma unroll
        for (int k = 0; k < 4; ++k) acc[b4][k] = fmaf(q[k], w2, acc[b4][k]);
      }
    }
    unsigned short* wt = WT + (size_t)o * 1024 + i0;
#pragma unroll
    for (int q = 0; q < 4; ++q) *(ushort8*)(wt + q * 8) = wb[q];
    float* p = partial + (size_t)(bid >> 2) * 32768 + o;
#pragma unroll
    for (int b4 = 0; b4 < 8; ++b4)
#pragma unroll
      for (int k = 0; k < 4; ++k) p[(b4 * 4 + k) * 1024] = acc[b4][k];
  } else {
    // ---- xconv ----
    const size_t total = (size_t)8388608;  // 32*1024*1024/4
    for (size_t g = (size_t)(bid - 128) * 256 + threadIdx.x; g < total;
         g += (size_t)2048 * 256) {
      float4 v = E4[g];
      size_t e = g * 4;
      int i = (int)(e & 1023);
      int b = (int)(e >> 20);
      float4 yv = *(const float4*)(y + b * 1024 + i);
      ushort4 o;
      o.x = f2bf(v.x * yv.x * 0.03125f);
      o.y = f2bf(v.y * yv.y * 0.03125f);
      o.z = f2bf(v.z * yv.z * 0.03125f);
      o.w = f2bf(v.w * yv.w * 0.03125f);
      *(ushort4*)(X + e) = o;
    }
  }
}

// ---------------------------------------------------------------------------
// GEMM: out[m,o] = (X @ W)[m,o] * rsqrt(sum_is dpart[is][b][o] + eps)
// r9 schedule (verified), MFMA switched to 32x32x16 (m119: +15% pipe, half
// the issue slots). 256x256 tile, BK=64, 8 waves 2Mx4N, per-wave 128x64 =
// 4Mx2N frags of 32x32. Deep staging: B(t+1) ph1/2, A(t+2) ph3/4, ONE VM(4)
// per K-tile. Same LDS format + 8-slot XOR swizzle (pre-swizzled source).
// Frag maps: A/B lane=(l&31) row, k=ks*16+(l>>5)*8+j; C/D col(N)=l&31,
// row(M)=(reg&3)+8*(reg>>2)+4*(l>>5)  [m74/m101].
// ---------------------------------------------------------------------------
#define NT 16           // K / BK
#define LDS_TILE 65536  // per-buffer: A 32KB + B 32KB

#define BAR __builtin_amdgcn_s_barrier()
#define LGKM0 asm volatile("s_waitcnt lgkmcnt(0)" ::: "memory")
#define VM(n) asm volatile("s_waitcnt vmcnt(" #n ")" ::: "memory")
#define SCHB __builtin_amdgcn_sched_barrier(0)
#define PRIO(x) __builtin_amdgcn_s_setprio(x)

#define STG_A(r, t, dst)                                                     \
  __builtin_amdgcn_global_load_lds(                                          \
      (const AS1 void*)(Xs + (size_t)(r) * 64 * 2048 + (t) * 128),           \
      (AS3 void*)((dst) + (r) * 8192 + sldso), 16, 0, 0)
#define STG_B(r, t, dst)                                                     \
  __builtin_amdgcn_global_load_lds(                                          \
      (const AS1 void*)(Ws + (size_t)(r) * 64 * 2048 + (t) * 128),           \
      (AS3 void*)((dst) + 32768 + (r) * 8192 + sldso), 16, 0, 0)

// 32x32 fragment reads; row&7 == l&7 for all frags -> swz32 = (l&7)<<4
#define RD_A(mh, mi, ks)                                                     \
  (*(const bf16x8*)(Ab + (wr * 128 + ((mh) * 2 + (mi)) * 32 + l31) * 128 +   \
                    ((((ks) * 32 + lq * 16)) ^ swz32)))
#define RD_B(nh, ks)                                                         \
  (*(const bf16x8*)(Bb + (wc * 64 + (nh) * 32 + l31) * 128 +                 \
                    ((((ks) * 32 + lq * 16)) ^ swz32)))

#define LD_A(mh)                                                             \
  { _Pragma("unroll") for (int mi = 0; mi < 2; ++mi)                         \
      _Pragma("unroll") for (int ks = 0; ks < 4; ++ks)                       \
        a[mi][ks] = RD_A(mh, mi, ks); }
#define LD_B(nh)                                                             \
  { _Pragma("unroll") for (int ks = 0; ks < 4; ++ks) bfr[ks] = RD_B(nh, ks); }

#define MM(mh, nh)                                                           \
  do {                                                                       \
    _Pragma("unroll") for (int mi = 0; mi < 2; ++mi)                         \
      _Pragma("unroll") for (int ks = 0; ks < 4; ++ks)                       \
        acc[(mh) * 2 + mi][nh] = __builtin_amdgcn_mfma_f32_32x32x16_bf16(    \
            a[mi][ks], bfr[ks], acc[(mh) * 2 + mi][nh], 0, 0, 0);            \
  } while (0)

__global__ __launch_bounds__(512, 2) void gemm32_kernel(
    const unsigned short* __restrict__ X, const unsigned short* __restrict__ WT,
    const float* __restrict__ dpart, float* __restrict__ out) {
  extern __shared__ char lds[];
  float* dtab = (float*)(lds + 2 * LDS_TILE);  // 1KB: d for this block's cols

  const int tid = threadIdx.x;
  const int bid = blockIdx.x;                  // 0..511
  const int wg = (bid & 7) * 64 + (bid >> 3);  // bijective XCD swizzle
  const int bm = wg >> 2, bn = wg & 3;
  const int m0 = bm * 256, n0 = bn * 256;
  const int b = m0 >> 10;  // 256 | 1024 -> uniform per block

  const int w = tid >> 6, l = tid & 63;
  const int wr = w >> 2, wc = w & 3;  // 2M x 4N waves, per-wave 128x64
  const int l31 = l & 31, lq = l >> 5;
  const int swz32 = (l & 7) << 4;

  // staging: LDS written linearly; SOURCE column pre-swizzled (rule #21)
  const int srow = tid >> 3;
  const int scb = ((tid & 7) << 4) ^ ((srow & 7) << 4);
  const char* Xs = (const char*)X + (size_t)(m0 + srow) * 2048 + scb;
  const char* Ws = (const char*)WT + (size_t)(n0 + srow) * 2048 + scb;
  const int sldso = tid * 16;

  f32x16 acc[4][2] = {};
  bf16x8 a[2][4], bfr[4];

  char* buf0 = lds;
  char* buf1 = lds + LDS_TILE;

  // ---- prologue A: fold dcalc_b -- dtab[c] = rsqrt(sum_is dpart + eps) ----
  if (tid < 256) {
    const float* dp = dpart + b * 1024 + n0 + tid;
    float s = 0.f;
#pragma unroll 8
    for (int is = 0; is < 32; ++is) s += dp[(size_t)is * 32768];
    dtab[tid] = rsqrtf(s + 1e-8f);
  }
  __syncthreads();  // dtab published; compiler drained dpart loads

  // ---- prologue B: tile0 full (8) + A(1) (4) = 12 in flight ----
  STG_A(0, 0, buf0); STG_A(2, 0, buf0); STG_A(1, 0, buf0); STG_A(3, 0, buf0);
  STG_B(0, 0, buf0); STG_B(1, 0, buf0); STG_B(2, 0, buf0); STG_B(3, 0, buf0);
  STG_A(0, 1, buf1); STG_A(2, 1, buf1); STG_A(1, 1, buf1); STG_A(3, 1, buf1);
  VM(4);
  BAR;

  // steady tiles 0..13: B(t+1) at ph1/2, A(t+2) at ph3/4, VM(4) at ph4 end
  for (int t = 0; t < NT - 2; ++t) {
    const char* Ab = lds + (t & 1) * LDS_TILE;
    const char* Bb = Ab + 32768;
    char* dB = lds + ((t + 1) & 1) * LDS_TILE;  // B(t+1) dest
    char* dA = lds + (t & 1) * LDS_TILE;        // A(t+2) dest (current buf)
    const int t1 = t + 1, t2 = t + 2;
    // ph1: reads A0/A1-half, B0; stages B0,B1(t+1)
    LD_A(0); LD_B(0);
    STG_B(0, t1, dB); STG_B(1, t1, dB);
    BAR; LGKM0; SCHB; PRIO(1); MM(0, 0); PRIO(0); SCHB; BAR;
    // ph2: stages B2,B3(t+1)
    LD_B(1);
    STG_B(2, t1, dB); STG_B(3, t1, dB);
    BAR; LGKM0; SCHB; PRIO(1); MM(0, 1); PRIO(0); SCHB; BAR;
    // ph3: reads A-half 1; stages A0,A2(t+2) into regions freed after ph2
    LD_A(1); LD_B(0);
    STG_A(0, t2, dA); STG_A(2, t2, dA);
    BAR; LGKM0; SCHB; PRIO(1); MM(1, 0); PRIO(0); SCHB; BAR;
    // ph4: stages A1,A3(t+2) into regions freed after ph3
    LD_B(1);
    STG_A(1, t2, dA); STG_A(3, t2, dA);
    BAR; LGKM0; SCHB; PRIO(1); MM(1, 1); PRIO(0); SCHB;
    VM(4);  // oldest 8 = A(t+1)x4 + B(t+1)x4 done; A(t+2)x4 stay in flight
    BAR;
  }

  // tile 14: stage B(15) only; drain all at end
  {
    const int t = NT - 2;
    const char* Ab = lds + (t & 1) * LDS_TILE;
    const char* Bb = Ab + 32768;
    char* dB = lds + ((t + 1) & 1) * LDS_TILE;
    const int t1 = t + 1;
    LD_A(0); LD_B(0);
    STG_B(0, t1, dB); STG_B(1, t1, dB);
    BAR; LGKM0; SCHB; PRIO(1); MM(0, 0); PRIO(0); SCHB; BAR;
    LD_B(1);
    STG_B(2, t1, dB); STG_B(3, t1, dB);
    BAR; LGKM0; SCHB; PRIO(1); MM(0, 1); PRIO(0); SCHB; BAR;
    LD_A(1); LD_B(0);
    BAR; LGKM0; SCHB; PRIO(1); MM(1, 0); PRIO(0); SCHB; BAR;
    LD_B(1);
    BAR; LGKM0; SCHB; PRIO(1); MM(1, 1); PRIO(0); SCHB;
    VM(0);
    BAR;
  }

  // tile 15: bare compute
  {
    const char* Ab = lds + ((NT - 1) & 1) * LDS_TILE;
    const char* Bb = Ab + 32768;
    LD_A(0); LD_B(0);
    BAR; LGKM0; SCHB; PRIO(1); MM(0, 0); PRIO(0); SCHB; BAR;
    LD_B(1);
    BAR; LGKM0; SCHB; PRIO(1); MM(0, 1); PRIO(0); SCHB; BAR;
    LD_A(1); LD_B(0);
    BAR; LGKM0; SCHB; PRIO(1); MM(1, 0); PRIO(0); SCHB; BAR;
    LD_B(1);
    BAR; LGKM0; SCHB; PRIO(1); MM(1, 1); PRIO(0); SCHB;
  }

  // epilogue: 32x32 C/D: col(N)=l31, row(M)=(reg&3)+8*(reg>>2)+4*lq
  float dvv[2];
#pragma unroll
  for (int nf = 0; nf < 2; ++nf) dvv[nf] = dtab[wc * 64 + nf * 32 + l31];
#pragma unroll
  for (int mf = 0; mf < 4; ++mf) {
#pragma unroll
    for (int nf = 0; nf < 2; ++nf) {
      const int col = n0 + wc * 64 + nf * 32 + l31;
#pragma unroll
      for (int reg = 0; reg < 16; ++reg) {
        const int row =
            m0 + wr * 128 + mf * 32 + (reg & 3) + 8 * (reg >> 2) + 4 * lq;
        out[(size_t)row * 1024 + col] = acc[mf][nf][reg] * dvv[nf];
      }
    }
  }
}

// ---------------------------------------------------------------------------
extern "C" void kernel_launch(void* const* d_in, const int* in_sizes, int n_in,
                              void* d_out, int out_size, void* d_ws, size_t ws_size,
                              hipStream_t stream) {
  const float* Efou = (const float*)d_in[0];  // 32*1024*1024 fp32
  const float* y    = (const float*)d_in[1];  // 32*1024 fp32
  const float* W    = (const float*)d_in[2];  // 1024*1024 fp32
  float* out = (float*)d_out;

  unsigned short* X  = (unsigned short*)d_ws;               // 64 MB bf16
  unsigned short* WT = X + (size_t)32768 * 1024;            // 2 MB bf16
  float* dpart       = (float*)(WT + (size_t)1024 * 1024);  // 4 MB fp32

  hipFuncSetAttribute((const void*)gemm32_kernel,
                      hipFuncAttributeMaxDynamicSharedMemorySize, 132096);

  prepx_kernel<<<2176, 256, 0, stream>>>(y, W, (const float4*)Efou, dpart, WT, X);
  gemm32_kernel<<<512, 512, 132096, stream>>>(X, WT, dpart, out);
}

// Round 11
// 134.291 us; speedup vs baseline: 1.1363x; 1.1363x over previous
//
#include <hip/hip_runtime.h>

#define AS1 __attribute__((address_space(1)))
#define AS3 __attribute__((address_space(3)))

typedef __bf16 bf16x8 __attribute__((ext_vector_type(8)));
typedef float f32x4 __attribute__((ext_vector_type(4)));
typedef unsigned short ushort8 __attribute__((ext_vector_type(8)));

// round-to-nearest-even f32 -> bf16
__device__ __forceinline__ unsigned short f2bf(float f) {
  union { float f; unsigned u; } v; v.f = f;
  unsigned u = v.u;
  unsigned r = (u + 0x7fffu + ((u >> 16) & 1u)) >> 16;
  return (unsigned short)r;
}

// ---------------------------------------------------------------------------
// prep: fused dcalc_a + wconv (r8/r9-verified). Grid (4,32), block 256.
// Each W element read ONCE: partial[is][b][o] += ysq[b,i]*W^2 (32 indep FMA
// chains hide latency) AND WT[o][i] = bf16(W[i,o]).
// ---------------------------------------------------------------------------
__global__ __launch_bounds__(256) void prep_kernel(const float* __restrict__ y,
                                                   const float* __restrict__ W,
                                                   float* __restrict__ partial,
                                                   unsigned short* __restrict__ WT) {
  __shared__ float ysq[32][32];  // [i_local][b]
  const int o = blockIdx.x * 256 + threadIdx.x;
  const int i0 = blockIdx.y * 32;
  for (int e = threadIdx.x; e < 1024; e += 256) {
    int il = e >> 5, b = e & 31;
    float t = y[b * 1024 + i0 + il] * 0.03125f;
    ysq[il][b] = t * t;
  }
  __syncthreads();

  f32x4 acc[8] = {};
  ushort8 wb[4];
#pragma unroll
  for (int il = 0; il < 32; ++il) {
    float w = W[(size_t)(i0 + il) * 1024 + o];
    wb[il >> 3][il & 7] = f2bf(w);
    float w2 = w * w;
#pragma unroll
    for (int b4 = 0; b4 < 8; ++b4) {
      f32x4 q = *(const f32x4*)&ysq[il][b4 * 4];
#pragma unroll
      for (int k = 0; k < 4; ++k) acc[b4][k] = fmaf(q[k], w2, acc[b4][k]);
    }
  }
  unsigned short* wt = WT + (size_t)o * 1024 + i0;
#pragma unroll
  for (int q = 0; q < 4; ++q) *(ushort8*)(wt + q * 8) = wb[q];
  float* p = partial + (size_t)blockIdx.y * 32768 + o;
#pragma unroll
  for (int b4 = 0; b4 < 8; ++b4)
#pragma unroll
    for (int k = 0; k < 4; ++k) p[(b4 * 4 + k) * 1024] = acc[b4][k];
}

// ---------------------------------------------------------------------------
// Fused GEMM (r4-verified schedule + r9-verified dtab fold):
// out[m,o] = ((Efou*ys) @ W)[m,o] * rsqrt(sum_is dpart[is][b][o] + eps)
// A: fp32 Efou -> regs -> (*ys, bf16 RNE) -> swizzled ds_write (fused; no X
// buffer, no xconv pass). B: pre-swizzled-source global_load_lds.
// 256x256 tile, BK=64, 8 waves 2Mx4N, 16x16x32 MFMA, XCD swizzle, setprio.
// ---------------------------------------------------------------------------
#define NT 16           // K / BK
#define LDS_TILE 65536  // per-buffer: A 32KB + B 32KB

#define BAR __builtin_amdgcn_s_barrier()
#define LGKM0 asm volatile("s_waitcnt lgkmcnt(0)" ::: "memory")
#define VM(n) asm volatile("s_waitcnt vmcnt(" #n ")" ::: "memory")
#define SCHB __builtin_amdgcn_sched_barrier(0)
#define PRIO(x) __builtin_amdgcn_s_setprio(x)

// stage one 64-row half (8KB) of B for K-tile t into dst buffer
#define STG_B(r, t, dst)                                                     \
  __builtin_amdgcn_global_load_lds(                                          \
      (const AS1 void*)(Ws + (size_t)(r) * 64 * 2048 + (t) * 128),           \
      (AS3 void*)((dst) + 32768 + (r) * 8192 + sldso), 16, 0, 0)

// issue A fp32 loads (4 rows x 8 k) + ys reads for K-tile t
#define A_ISSUE(t)                                                           \
  {                                                                          \
    const float* asrc = Efou + (size_t)(m0 + argp * 4) * 1024 + (t) * 64 + k8; \
    _Pragma("unroll") for (int rr = 0; rr < 4; ++rr) {                       \
      pa[rr][0] = *(const f32x4*)(asrc + rr * 1024);                         \
      pa[rr][1] = *(const f32x4*)(asrc + rr * 1024 + 4);                     \
    }                                                                        \
    yv[0] = *(const f32x4*)(ysS + (t) * 64 + k8);                            \
    yv[1] = *(const f32x4*)(ysS + (t) * 64 + k8 + 4);                        \
  }

// convert (*ys -> bf16, RNE) and swizzled ds_write into dst A region
#define ACVT_WR(dst)                                                         \
  {                                                                          \
    _Pragma("unroll") for (int rr = 0; rr < 4; ++rr) {                       \
      const int row = argp * 4 + rr;                                         \
      ushort8 ov;                                                            \
      _Pragma("unroll") for (int q = 0; q < 4; ++q) {                        \
        ov[q] = f2bf(pa[rr][0][q] * yv[0][q]);                               \
        ov[q + 4] = f2bf(pa[rr][1][q] * yv[1][q]);                           \
      }                                                                      \
      *(ushort8*)((dst) + row * 128 + ((kslot * 16) ^ ((row & 7) << 4))) = ov; \
    }                                                                        \
  }

// swizzled fragment reads (row&7 == l15&7 for all frags)
#define RD_A(mh, mi, kk)                                                     \
  (*(const bf16x8*)(Ab + (wr * 128 + ((mh) * 4 + (mi)) * 16 + l15) * 128 +   \
                    ((((kk) * 64 + lhi * 16)) ^ swz_rd)))
#define RD_B(nh, ni, kk)                                                     \
  (*(const bf16x8*)(Bb + (wc * 64 + ((nh) * 2 + (ni)) * 16 + l15) * 128 +    \
                    ((((kk) * 64 + lhi * 16)) ^ swz_rd)))

#define LD_A(mh)                                                             \
  { _Pragma("unroll") for (int mi = 0; mi < 4; ++mi)                         \
      _Pragma("unroll") for (int kk = 0; kk < 2; ++kk)                       \
        a[mi][kk] = RD_A(mh, mi, kk); }
#define LD_B(nh)                                                             \
  { _Pragma("unroll") for (int ni = 0; ni < 2; ++ni)                         \
      _Pragma("unroll") for (int kk = 0; kk < 2; ++kk)                       \
        bfr[ni][kk] = RD_B(nh, ni, kk); }

#define MM(mh, nh)                                                           \
  do {                                                                       \
    _Pragma("unroll") for (int mi = 0; mi < 4; ++mi)                         \
      _Pragma("unroll") for (int ni = 0; ni < 2; ++ni)                       \
        _Pragma("unroll") for (int kk = 0; kk < 2; ++kk)                     \
          acc[(mh) * 4 + mi][(nh) * 2 + ni] =                                \
              __builtin_amdgcn_mfma_f32_16x16x32_bf16(                       \
                  a[mi][kk], bfr[ni][kk], acc[(mh) * 4 + mi][(nh) * 2 + ni], \
                  0, 0, 0);                                                  \
  } while (0)

__global__ __launch_bounds__(512, 2) void gemmf3_kernel(
    const float* __restrict__ Efou, const float* __restrict__ y,
    const unsigned short* __restrict__ WT, const float* __restrict__ dpart,
    float* __restrict__ out) {
  extern __shared__ char lds[];
  float* ysS = (float*)(lds + 2 * LDS_TILE);   // 4KB ys table
  float* dtab = (float*)(lds + 2 * LDS_TILE + 4096);  // 1KB d table

  const int tid = threadIdx.x;
  const int bid = blockIdx.x;                  // 0..511
  const int wg = (bid & 7) * 64 + (bid >> 3);  // bijective XCD swizzle
  const int bm = wg >> 2, bn = wg & 3;
  const int m0 = bm * 256, n0 = bn * 256;
  const int b = m0 >> 10;  // uniform per block (256 | 1024)

  const int w = tid >> 6, l = tid & 63;
  const int wr = w >> 2, wc = w & 3;  // 2M x 4N waves
  const int l15 = l & 15, lhi = l >> 4;
  const int swz_rd = (l15 & 7) << 4;

  // A reg-staging geometry: 4 rows x 8 k per thread
  const int kslot = tid & 7;
  const int k8 = kslot * 8;
  const int argp = tid >> 3;  // rows argp*4..+3

  // B staging: LDS written linearly; SOURCE column pre-swizzled (rule #21)
  const int srow = tid >> 3;
  const int scb = ((tid & 7) << 4) ^ ((srow & 7) << 4);
  const char* Ws = (const char*)WT + (size_t)(n0 + srow) * 2048 + scb;
  const int sldso = tid * 16;

  f32x4 acc[8][4] = {};
  bf16x8 a[4][2], bfr[2][2];
  f32x4 pa[4][2], yv[2];

  // ---- prologue: dtab (dcalc_b fold, r9 pattern) + ysS table ----
  if (tid < 256) {
    const float* dp = dpart + b * 1024 + n0 + tid;
    float s = 0.f;
#pragma unroll 8
    for (int is = 0; is < 32; ++is) s += dp[(size_t)is * 32768];
    dtab[tid] = rsqrtf(s + 1e-8f);
  }
  {
    float2 yy = *(const float2*)(y + b * 1024 + tid * 2);
    ysS[2 * tid] = yy.x * 0.03125f;
    ysS[2 * tid + 1] = yy.y * 0.03125f;
  }
  __syncthreads();  // publish ysS + dtab; compiler drained dpart loads
  {
    char* d0 = lds;
    STG_B(0, 0, d0); STG_B(1, 0, d0); STG_B(2, 0, d0); STG_B(3, 0, d0);
    A_ISSUE(0);
    A_WRITE_PROLOGUE:
    ACVT_WR(d0);  // compiler auto-waits the A loads
  }
  VM(0); LGKM0; BAR;

  // ---- main loop (r4-verified) ----
  for (int t = 0; t < NT - 1; ++t) {
    const char* Ab = lds + (t & 1) * LDS_TILE;
    const char* Bb = Ab + 32768;
    char* dN = lds + ((t & 1) ^ 1) * LDS_TILE;
    const int t1 = t + 1;
    // phase 1: quadrant (mh0, nh0); issue next A loads + 2 B stages
    LD_A(0); LD_B(0);
    A_ISSUE(t1);
    STG_B(0, t1, dN); STG_B(1, t1, dN);
    BAR; LGKM0; SCHB; PRIO(1); MM(0, 0); PRIO(0); SCHB; BAR;
    // phase 2: (mh0, nh1); 2 more B stages
    LD_B(1);
    STG_B(2, t1, dN); STG_B(3, t1, dN);
    BAR; LGKM0; SCHB; PRIO(1); MM(0, 1); PRIO(0); SCHB; BAR;
    // phase 3: (mh1, nh0); convert+write off the publish path
    LD_A(1); LD_B(0);
    ACVT_WR(dN);  // compiler waits the A loads (2 phases of cover)
    BAR; LGKM0; SCHB; PRIO(1); MM(1, 0); PRIO(0); SCHB; BAR;
    // phase 4: (mh1, nh1); then publish
    LD_B(1);
    BAR; LGKM0; SCHB; PRIO(1); MM(1, 1); PRIO(0); SCHB;
    VM(0);         // B gload_lds for t+1 complete
    LGKM0;         // ds_writes visible before publish barrier
    BAR;
  }

  // ---- peeled last K-tile (no staging) ----
  {
    const char* Ab = lds + ((NT - 1) & 1) * LDS_TILE;
    const char* Bb = Ab + 32768;
    LD_A(0); LD_B(0);
    BAR; LGKM0; SCHB; PRIO(1); MM(0, 0); PRIO(0); SCHB; BAR;
    LD_B(1);
    BAR; LGKM0; SCHB; PRIO(1); MM(0, 1); PRIO(0); SCHB; BAR;
    LD_A(1); LD_B(0);
    BAR; LGKM0; SCHB; PRIO(1); MM(1, 0); PRIO(0); SCHB; BAR;
    LD_B(1);
    BAR; LGKM0; SCHB; PRIO(1); MM(1, 1); PRIO(0); SCHB;
  }

  // ---- epilogue: C/D layout col=l&15, row=(l>>4)*4+j; scale by dtab ----
  const int lc0 = wc * 64 + l15;
  float dv[4];
#pragma unroll
  for (int nf = 0; nf < 4; ++nf) dv[nf] = dtab[lc0 + nf * 16];
#pragma unroll
  for (int mf = 0; mf < 8; ++mf) {
#pragma unroll
    for (int j = 0; j < 4; ++j) {
      const int row = m0 + wr * 128 + mf * 16 + lhi * 4 + j;
      float* orow = out + (size_t)row * 1024 + n0 + lc0;
#pragma unroll
      for (int nf = 0; nf < 4; ++nf) orow[nf * 16] = acc[mf][nf][j] * dv[nf];
    }
  }
}

// ---------------------------------------------------------------------------
extern "C" void kernel_launch(void* const* d_in, const int* in_sizes, int n_in,
                              void* d_out, int out_size, void* d_ws, size_t ws_size,
                              hipStream_t stream) {
  const float* Efou = (const float*)d_in[0];  // 32*1024*1024 fp32
  const float* y    = (const float*)d_in[1];  // 32*1024 fp32
  const float* W    = (const float*)d_in[2];  // 1024*1024 fp32
  float* out = (float*)d_out;

  unsigned short* WT = (unsigned short*)d_ws;               // 2 MB bf16
  float* dpart       = (float*)(WT + (size_t)1024 * 1024);  // 4 MB fp32

  hipFuncSetAttribute((const void*)gemmf3_kernel,
                      hipFuncAttributeMaxDynamicSharedMemorySize, 136192);

  prep_kernel<<<dim3(4, 32), 256, 0, stream>>>(y, W, dpart, WT);
  gemmf3_kernel<<<512, 512, 136192, stream>>>(Efou, y, WT, dpart, out);
}

// Round 12
// 127.947 us; speedup vs baseline: 1.1927x; 1.0496x over previous
//
#include <hip/hip_runtime.h>

#define AS1 __attribute__((address_space(1)))
#define AS3 __attribute__((address_space(3)))

typedef __bf16 bf16x8 __attribute__((ext_vector_type(8)));
typedef float f32x4 __attribute__((ext_vector_type(4)));
typedef unsigned short ushort8 __attribute__((ext_vector_type(8)));

// round-to-nearest-even f32 -> bf16
__device__ __forceinline__ unsigned short f2bf(float f) {
  union { float f; unsigned u; } v; v.f = f;
  unsigned u = v.u;
  unsigned r = (u + 0x7fffu + ((u >> 16) & 1u)) >> 16;
  return (unsigned short)r;
}

// ---------------------------------------------------------------------------
// prep: fused dcalc_a + wconv (r9-verified). Grid (4,32), block 256.
// Each W element read ONCE: partial[is][b][o] += ysq[b,i]*W^2 (32 indep FMA
// chains hide latency) AND WT[o][i] = bf16(W[i,o]).
// ---------------------------------------------------------------------------
__global__ __launch_bounds__(256) void prep_kernel(const float* __restrict__ y,
                                                   const float* __restrict__ W,
                                                   float* __restrict__ partial,
                                                   unsigned short* __restrict__ WT) {
  __shared__ float ysq[32][32];  // [i_local][b]
  const int o = blockIdx.x * 256 + threadIdx.x;
  const int i0 = blockIdx.y * 32;
  for (int e = threadIdx.x; e < 1024; e += 256) {
    int il = e >> 5, b = e & 31;
    float t = y[b * 1024 + i0 + il] * 0.03125f;
    ysq[il][b] = t * t;
  }
  __syncthreads();

  f32x4 acc[8] = {};
  ushort8 wb[4];
#pragma unroll
  for (int il = 0; il < 32; ++il) {
    float w = W[(size_t)(i0 + il) * 1024 + o];
    wb[il >> 3][il & 7] = f2bf(w);
    float w2 = w * w;
#pragma unroll
    for (int b4 = 0; b4 < 8; ++b4) {
      f32x4 q = *(const f32x4*)&ysq[il][b4 * 4];
#pragma unroll
      for (int k = 0; k < 4; ++k) acc[b4][k] = fmaf(q[k], w2, acc[b4][k]);
    }
  }
  unsigned short* wt = WT + (size_t)o * 1024 + i0;
#pragma unroll
  for (int q = 0; q < 4; ++q) *(ushort8*)(wt + q * 8) = wb[q];
  float* p = partial + (size_t)blockIdx.y * 32768 + o;
#pragma unroll
  for (int b4 = 0; b4 < 8; ++b4)
#pragma unroll
    for (int k = 0; k < 4; ++k) p[(b4 * 4 + k) * 1024] = acc[b4][k];
}

// ---------------------------------------------------------------------------
// dcalc_b (r3-verified): dmod[b,o] = rsqrt( sum_is partial[is][b][o] + eps )
// ---------------------------------------------------------------------------
__global__ __launch_bounds__(256) void dcalc_b_kernel(const float* __restrict__ partial,
                                                      float* __restrict__ dmod) {
  const int bo = blockIdx.x * 256 + threadIdx.x;
  float acc = 0.f;
#pragma unroll 8
  for (int is = 0; is < 32; ++is) acc += partial[(size_t)is * 32768 + bo];
  dmod[bo] = rsqrtf(acc + 1e-8f);
}

// ---------------------------------------------------------------------------
// Fused GEMM (r4-verified schedule; ONE edit: ph3 ACVT_WR moved inside the
// MFMA region so the cvt VALU fills MFMA issue gaps instead of serializing
// in the load phase): out[m,o] = ((Efou*ys) @ W)[m,o] * dmod[b,o].
// A: fp32 Efou -> regs -> (*ys, bf16 RNE) -> swizzled ds_write.
// B: pre-swizzled-source global_load_lds. 256x256, BK=64, 8 waves 2Mx4N.
// ---------------------------------------------------------------------------
#define NT 16           // K / BK
#define LDS_TILE 65536  // per-buffer: A 32KB + B 32KB

#define BAR __builtin_amdgcn_s_barrier()
#define LGKM0 asm volatile("s_waitcnt lgkmcnt(0)" ::: "memory")
#define VM(n) asm volatile("s_waitcnt vmcnt(" #n ")" ::: "memory")
#define SCHB __builtin_amdgcn_sched_barrier(0)
#define PRIO(x) __builtin_amdgcn_s_setprio(x)

// stage one 64-row half (8KB) of B for K-tile t into dst buffer
#define STG_B(r, t, dst)                                                     \
  __builtin_amdgcn_global_load_lds(                                          \
      (const AS1 void*)(Ws + (size_t)(r) * 64 * 2048 + (t) * 128),           \
      (AS3 void*)((dst) + 32768 + (r) * 8192 + sldso), 16, 0, 0)

// issue A fp32 loads (4 rows x 8 k) + ys reads for K-tile t
#define A_ISSUE(t)                                                           \
  {                                                                          \
    const float* asrc = Efou + (size_t)(m0 + argp * 4) * 1024 + (t) * 64 + k8; \
    _Pragma("unroll") for (int rr = 0; rr < 4; ++rr) {                       \
      pa[rr][0] = *(const f32x4*)(asrc + rr * 1024);                         \
      pa[rr][1] = *(const f32x4*)(asrc + rr * 1024 + 4);                     \
    }                                                                        \
    yv[0] = *(const f32x4*)(ysS + (t) * 64 + k8);                            \
    yv[1] = *(const f32x4*)(ysS + (t) * 64 + k8 + 4);                        \
  }

// convert (*ys -> bf16, RNE) and swizzled ds_write into dst A region
#define ACVT_WR(dst)                                                         \
  {                                                                          \
    _Pragma("unroll") for (int rr = 0; rr < 4; ++rr) {                       \
      const int row = argp * 4 + rr;                                         \
      ushort8 ov;                                                            \
      _Pragma("unroll") for (int q = 0; q < 4; ++q) {                        \
        ov[q] = f2bf(pa[rr][0][q] * yv[0][q]);                               \
        ov[q + 4] = f2bf(pa[rr][1][q] * yv[1][q]);                           \
      }                                                                      \
      *(ushort8*)((dst) + row * 128 + ((kslot * 16) ^ ((row & 7) << 4))) = ov; \
    }                                                                        \
  }

// swizzled fragment reads (row&7 == l15&7 for all frags)
#define RD_A(mh, mi, kk)                                                     \
  (*(const bf16x8*)(Ab + (wr * 128 + ((mh) * 4 + (mi)) * 16 + l15) * 128 +   \
                    ((((kk) * 64 + lhi * 16)) ^ swz_rd)))
#define RD_B(nh, ni, kk)                                                     \
  (*(const bf16x8*)(Bb + (wc * 64 + ((nh) * 2 + (ni)) * 16 + l15) * 128 +    \
                    ((((kk) * 64 + lhi * 16)) ^ swz_rd)))

#define LD_A(mh)                                                             \
  { _Pragma("unroll") for (int mi = 0; mi < 4; ++mi)                         \
      _Pragma("unroll") for (int kk = 0; kk < 2; ++kk)                       \
        a[mi][kk] = RD_A(mh, mi, kk); }
#define LD_B(nh)                                                             \
  { _Pragma("unroll") for (int ni = 0; ni < 2; ++ni)                         \
      _Pragma("unroll") for (int kk = 0; kk < 2; ++kk)                       \
        bfr[ni][kk] = RD_B(nh, ni, kk); }

#define MM(mh, nh)                                                           \
  do {                                                                       \
    _Pragma("unroll") for (int mi = 0; mi < 4; ++mi)                         \
      _Pragma("unroll") for (int ni = 0; ni < 2; ++ni)                       \
        _Pragma("unroll") for (int kk = 0; kk < 2; ++kk)                     \
          acc[(mh) * 4 + mi][(nh) * 2 + ni] =                                \
              __builtin_amdgcn_mfma_f32_16x16x32_bf16(                       \
                  a[mi][kk], bfr[ni][kk], acc[(mh) * 4 + mi][(nh) * 2 + ni], \
                  0, 0, 0);                                                  \
  } while (0)

__global__ __launch_bounds__(512, 2) void gemmf4_kernel(
    const float* __restrict__ Efou, const float* __restrict__ y,
    const unsigned short* __restrict__ WT, const float* __restrict__ dmod,
    float* __restrict__ out) {
  extern __shared__ char lds[];
  float* ysS = (float*)(lds + 2 * LDS_TILE);  // 4KB ys table

  const int tid = threadIdx.x;
  const int bid = blockIdx.x;                  // 0..511
  const int wg = (bid & 7) * 64 + (bid >> 3);  // bijective XCD swizzle
  const int bm = wg >> 2, bn = wg & 3;
  const int m0 = bm * 256, n0 = bn * 256;
  const int b = m0 >> 10;  // uniform per block (256 | 1024)

  const int w = tid >> 6, l = tid & 63;
  const int wr = w >> 2, wc = w & 3;  // 2M x 4N waves
  const int l15 = l & 15, lhi = l >> 4;
  const int swz_rd = (l15 & 7) << 4;

  // A reg-staging geometry: 4 rows x 8 k per thread
  const int kslot = tid & 7;
  const int k8 = kslot * 8;
  const int argp = tid >> 3;  // rows argp*4..+3

  // B staging: LDS written linearly; SOURCE column pre-swizzled (rule #21)
  const int srow = tid >> 3;
  const int scb = ((tid & 7) << 4) ^ ((srow & 7) << 4);
  const char* Ws = (const char*)WT + (size_t)(n0 + srow) * 2048 + scb;
  const int sldso = tid * 16;

  f32x4 acc[8][4] = {};
  bf16x8 a[4][2], bfr[2][2];
  f32x4 pa[4][2], yv[2];

  // ---- prologue ----
  {
    float2 yy = *(const float2*)(y + b * 1024 + tid * 2);
    ysS[2 * tid] = yy.x * 0.03125f;
    ysS[2 * tid + 1] = yy.y * 0.03125f;
  }
  __syncthreads();  // publish ysS
  {
    char* d0 = lds;
    STG_B(0, 0, d0); STG_B(1, 0, d0); STG_B(2, 0, d0); STG_B(3, 0, d0);
    A_ISSUE(0);
    ACVT_WR(d0);  // compiler auto-waits the A loads
  }
  VM(0); LGKM0; BAR;

  // ---- main loop (r4 schedule; ph3 cvt interleaved with MFMA) ----
  for (int t = 0; t < NT - 1; ++t) {
    const char* Ab = lds + (t & 1) * LDS_TILE;
    const char* Bb = Ab + 32768;
    char* dN = lds + ((t & 1) ^ 1) * LDS_TILE;
    const int t1 = t + 1;
    // phase 1: quadrant (mh0, nh0); issue next A loads + 2 B stages
    LD_A(0); LD_B(0);
    A_ISSUE(t1);
    STG_B(0, t1, dN); STG_B(1, t1, dN);
    BAR; LGKM0; SCHB; PRIO(1); MM(0, 0); PRIO(0); SCHB; BAR;
    // phase 2: (mh0, nh1); 2 more B stages
    LD_B(1);
    STG_B(2, t1, dN); STG_B(3, t1, dN);
    BAR; LGKM0; SCHB; PRIO(1); MM(0, 1); PRIO(0); SCHB; BAR;
    // phase 3: (mh1, nh0); cvt+ds_write INSIDE the MFMA region -- the cvt
    // VALU has no dep on the MFMA operands, scheduler fills issue gaps
    LD_A(1); LD_B(0);
    BAR; LGKM0; SCHB; PRIO(1);
    ACVT_WR(dN);
    MM(1, 0);
    PRIO(0); SCHB; BAR;
    // phase 4: (mh1, nh1); then publish
    LD_B(1);
    BAR; LGKM0; SCHB; PRIO(1); MM(1, 1); PRIO(0); SCHB;
    VM(0);         // B gload_lds for t+1 complete
    LGKM0;         // my ds_writes visible before publish barrier
    BAR;
  }

  // ---- peeled last K-tile (no staging) ----
  {
    const char* Ab = lds + ((NT - 1) & 1) * LDS_TILE;
    const char* Bb = Ab + 32768;
    LD_A(0); LD_B(0);
    BAR; LGKM0; SCHB; PRIO(1); MM(0, 0); PRIO(0); SCHB; BAR;
    LD_B(1);
    BAR; LGKM0; SCHB; PRIO(1); MM(0, 1); PRIO(0); SCHB; BAR;
    LD_A(1); LD_B(0);
    BAR; LGKM0; SCHB; PRIO(1); MM(1, 0); PRIO(0); SCHB; BAR;
    LD_B(1);
    BAR; LGKM0; SCHB; PRIO(1); MM(1, 1); PRIO(0); SCHB;
  }

  // ---- epilogue: C/D layout col=l&15, row=(l>>4)*4+j; scale by dmod ----
  const int col0 = n0 + wc * 64 + l15;
  float dv[4];
#pragma unroll
  for (int nf = 0; nf < 4; ++nf) dv[nf] = dmod[b * 1024 + col0 + nf * 16];
#pragma unroll
  for (int mf = 0; mf < 8; ++mf) {
#pragma unroll
    for (int j = 0; j < 4; ++j) {
      const int row = m0 + wr * 128 + mf * 16 + lhi * 4 + j;
      float* orow = out + (size_t)row * 1024 + col0;
#pragma unroll
      for (int nf = 0; nf < 4; ++nf) orow[nf * 16] = acc[mf][nf][j] * dv[nf];
    }
  }
}

// ---------------------------------------------------------------------------
extern "C" void kernel_launch(void* const* d_in, const int* in_sizes, int n_in,
                              void* d_out, int out_size, void* d_ws, size_t ws_size,
                              hipStream_t stream) {
  const float* Efou = (const float*)d_in[0];  // 32*1024*1024 fp32
  const float* y    = (const float*)d_in[1];  // 32*1024 fp32
  const float* W    = (const float*)d_in[2];  // 1024*1024 fp32
  float* out = (float*)d_out;

  unsigned short* WT = (unsigned short*)d_ws;               // 2 MB bf16
  float* dpart       = (float*)(WT + (size_t)1024 * 1024);  // 4 MB fp32
  float* dmod        = dpart + (size_t)32 * 32768;          // 128 KB fp32

  hipFuncSetAttribute((const void*)gemmf4_kernel,
                      hipFuncAttributeMaxDynamicSharedMemorySize, 135168);

  prep_kernel<<<dim3(4, 32), 256, 0, stream>>>(y, W, dpart, WT);
  dcalc_b_kernel<<<128, 256, 0, stream>>>(dpart, dmod);
  gemmf4_kernel<<<512, 512, 135168, stream>>>(Efou, y, WT, dmod, out);
}

// Round 13
// 127.513 us; speedup vs baseline: 1.1967x; 1.0034x over previous
//
#include <hip/hip_runtime.h>

#define AS1 __attribute__((address_space(1)))
#define AS3 __attribute__((address_space(3)))

typedef __bf16 bf16x8 __attribute__((ext_vector_type(8)));
typedef float f32x4 __attribute__((ext_vector_type(4)));
typedef unsigned short ushort8 __attribute__((ext_vector_type(8)));

// round-to-nearest-even f32 -> bf16 (used in prep only; hot path uses
// native __bf16 casts which the compiler lowers to v_cvt_pk_bf16_f32)
__device__ __forceinline__ unsigned short f2bf(float f) {
  union { float f; unsigned u; } v; v.f = f;
  unsigned u = v.u;
  unsigned r = (u + 0x7fffu + ((u >> 16) & 1u)) >> 16;
  return (unsigned short)r;
}

// ---------------------------------------------------------------------------
// prep: fused dcalc_a + wconv (r9-verified). Grid (4,32), block 256.
// Each W element read ONCE: partial[is][b][o] += ysq[b,i]*W^2 (32 indep FMA
// chains hide latency) AND WT[o][i] = bf16(W[i,o]).
// ---------------------------------------------------------------------------
__global__ __launch_bounds__(256) void prep_kernel(const float* __restrict__ y,
                                                   const float* __restrict__ W,
                                                   float* __restrict__ partial,
                                                   unsigned short* __restrict__ WT) {
  __shared__ float ysq[32][32];  // [i_local][b]
  const int o = blockIdx.x * 256 + threadIdx.x;
  const int i0 = blockIdx.y * 32;
  for (int e = threadIdx.x; e < 1024; e += 256) {
    int il = e >> 5, b = e & 31;
    float t = y[b * 1024 + i0 + il] * 0.03125f;
    ysq[il][b] = t * t;
  }
  __syncthreads();

  f32x4 acc[8] = {};
  ushort8 wb[4];
#pragma unroll
  for (int il = 0; il < 32; ++il) {
    float w = W[(size_t)(i0 + il) * 1024 + o];
    wb[il >> 3][il & 7] = f2bf(w);
    float w2 = w * w;
#pragma unroll
    for (int b4 = 0; b4 < 8; ++b4) {
      f32x4 q = *(const f32x4*)&ysq[il][b4 * 4];
#pragma unroll
      for (int k = 0; k < 4; ++k) acc[b4][k] = fmaf(q[k], w2, acc[b4][k]);
    }
  }
  unsigned short* wt = WT + (size_t)o * 1024 + i0;
#pragma unroll
  for (int q = 0; q < 4; ++q) *(ushort8*)(wt + q * 8) = wb[q];
  float* p = partial + (size_t)blockIdx.y * 32768 + o;
#pragma unroll
  for (int b4 = 0; b4 < 8; ++b4)
#pragma unroll
    for (int k = 0; k < 4; ++k) p[(b4 * 4 + k) * 1024] = acc[b4][k];
}

// ---------------------------------------------------------------------------
// dcalc_b (r3-verified): dmod[b,o] = rsqrt( sum_is partial[is][b][o] + eps )
// ---------------------------------------------------------------------------
__global__ __launch_bounds__(256) void dcalc_b_kernel(const float* __restrict__ partial,
                                                      float* __restrict__ dmod) {
  const int bo = blockIdx.x * 256 + threadIdx.x;
  float acc = 0.f;
#pragma unroll 8
  for (int is = 0; is < 32; ++is) acc += partial[(size_t)is * 32768 + bo];
  dmod[bo] = rsqrtf(acc + 1e-8f);
}

// ---------------------------------------------------------------------------
// Fused GEMM (r12-verified schedule; edits: native bf16 casts in the A
// convert, and the convert split across ph3/ph4 MFMA regions, 2 rows each):
// out[m,o] = ((Efou*ys) @ W)[m,o] * dmod[b,o].
// A: fp32 Efou -> regs -> (*ys, bf16 RNE) -> swizzled ds_write.
// B: pre-swizzled-source global_load_lds. 256x256, BK=64, 8 waves 2Mx4N.
// ---------------------------------------------------------------------------
#define NT 16           // K / BK
#define LDS_TILE 65536  // per-buffer: A 32KB + B 32KB

#define BAR __builtin_amdgcn_s_barrier()
#define LGKM0 asm volatile("s_waitcnt lgkmcnt(0)" ::: "memory")
#define VM(n) asm volatile("s_waitcnt vmcnt(" #n ")" ::: "memory")
#define SCHB __builtin_amdgcn_sched_barrier(0)
#define PRIO(x) __builtin_amdgcn_s_setprio(x)

// stage one 64-row half (8KB) of B for K-tile t into dst buffer
#define STG_B(r, t, dst)                                                     \
  __builtin_amdgcn_global_load_lds(                                          \
      (const AS1 void*)(Ws + (size_t)(r) * 64 * 2048 + (t) * 128),           \
      (AS3 void*)((dst) + 32768 + (r) * 8192 + sldso), 16, 0, 0)

// issue A fp32 loads (4 rows x 8 k) + ys reads for K-tile t
#define A_ISSUE(t)                                                           \
  {                                                                          \
    const float* asrc = Efou + (size_t)(m0 + argp * 4) * 1024 + (t) * 64 + k8; \
    _Pragma("unroll") for (int rr = 0; rr < 4; ++rr) {                       \
      pa[rr][0] = *(const f32x4*)(asrc + rr * 1024);                         \
      pa[rr][1] = *(const f32x4*)(asrc + rr * 1024 + 4);                     \
    }                                                                        \
    yv[0] = *(const f32x4*)(ysS + (t) * 64 + k8);                            \
    yv[1] = *(const f32x4*)(ysS + (t) * 64 + k8 + 4);                        \
  }

// convert one row (*ys -> bf16 via native cast) and swizzled ds_write
#define ACVT_ROW(dst, rr)                                                    \
  {                                                                          \
    const int row = argp * 4 + (rr);                                         \
    bf16x8 ov;                                                               \
    _Pragma("unroll") for (int q = 0; q < 4; ++q) {                          \
      ov[q] = (__bf16)(pa[rr][0][q] * yv[0][q]);                             \
      ov[q + 4] = (__bf16)(pa[rr][1][q] * yv[1][q]);                         \
    }                                                                        \
    *(bf16x8*)((dst) + row * 128 + ((kslot * 16) ^ ((row & 7) << 4))) = ov;  \
  }

// swizzled fragment reads (row&7 == l15&7 for all frags)
#define RD_A(mh, mi, kk)                                                     \
  (*(const bf16x8*)(Ab + (wr * 128 + ((mh) * 4 + (mi)) * 16 + l15) * 128 +   \
                    ((((kk) * 64 + lhi * 16)) ^ swz_rd)))
#define RD_B(nh, ni, kk)                                                     \
  (*(const bf16x8*)(Bb + (wc * 64 + ((nh) * 2 + (ni)) * 16 + l15) * 128 +    \
                    ((((kk) * 64 + lhi * 16)) ^ swz_rd)))

#define LD_A(mh)                                                             \
  { _Pragma("unroll") for (int mi = 0; mi < 4; ++mi)                         \
      _Pragma("unroll") for (int kk = 0; kk < 2; ++kk)                       \
        a[mi][kk] = RD_A(mh, mi, kk); }
#define LD_B(nh)                                                             \
  { _Pragma("unroll") for (int ni = 0; ni < 2; ++ni)                         \
      _Pragma("unroll") for (int kk = 0; kk < 2; ++kk)                       \
        bfr[ni][kk] = RD_B(nh, ni, kk); }

#define MM(mh, nh)                                                           \
  do {                                                                       \
    _Pragma("unroll") for (int mi = 0; mi < 4; ++mi)                         \
      _Pragma("unroll") for (int ni = 0; ni < 2; ++ni)                       \
        _Pragma("unroll") for (int kk = 0; kk < 2; ++kk)                     \
          acc[(mh) * 4 + mi][(nh) * 2 + ni] =                                \
              __builtin_amdgcn_mfma_f32_16x16x32_bf16(                       \
                  a[mi][kk], bfr[ni][kk], acc[(mh) * 4 + mi][(nh) * 2 + ni], \
                  0, 0, 0);                                                  \
  } while (0)

__global__ __launch_bounds__(512, 2) void gemmf5_kernel(
    const float* __restrict__ Efou, const float* __restrict__ y,
    const unsigned short* __restrict__ WT, const float* __restrict__ dmod,
    float* __restrict__ out) {
  extern __shared__ char lds[];
  float* ysS = (float*)(lds + 2 * LDS_TILE);  // 4KB ys table

  const int tid = threadIdx.x;
  const int bid = blockIdx.x;                  // 0..511
  const int wg = (bid & 7) * 64 + (bid >> 3);  // bijective XCD swizzle
  const int bm = wg >> 2, bn = wg & 3;
  const int m0 = bm * 256, n0 = bn * 256;
  const int b = m0 >> 10;  // uniform per block (256 | 1024)

  const int w = tid >> 6, l = tid & 63;
  const int wr = w >> 2, wc = w & 3;  // 2M x 4N waves
  const int l15 = l & 15, lhi = l >> 4;
  const int swz_rd = (l15 & 7) << 4;

  // A reg-staging geometry: 4 rows x 8 k per thread
  const int kslot = tid & 7;
  const int k8 = kslot * 8;
  const int argp = tid >> 3;  // rows argp*4..+3

  // B staging: LDS written linearly; SOURCE column pre-swizzled (rule #21)
  const int srow = tid >> 3;
  const int scb = ((tid & 7) << 4) ^ ((srow & 7) << 4);
  const char* Ws = (const char*)WT + (size_t)(n0 + srow) * 2048 + scb;
  const int sldso = tid * 16;

  f32x4 acc[8][4] = {};
  bf16x8 a[4][2], bfr[2][2];
  f32x4 pa[4][2], yv[2];

  // ---- prologue ----
  {
    float2 yy = *(const float2*)(y + b * 1024 + tid * 2);
    ysS[2 * tid] = yy.x * 0.03125f;
    ysS[2 * tid + 1] = yy.y * 0.03125f;
  }
  __syncthreads();  // publish ysS
  {
    char* d0 = lds;
    STG_B(0, 0, d0); STG_B(1, 0, d0); STG_B(2, 0, d0); STG_B(3, 0, d0);
    A_ISSUE(0);
    ACVT_ROW(d0, 0); ACVT_ROW(d0, 1); ACVT_ROW(d0, 2); ACVT_ROW(d0, 3);
  }
  VM(0); LGKM0; BAR;

  // ---- main loop (r12 schedule; cvt split across ph3/ph4 MFMA regions) ----
  for (int t = 0; t < NT - 1; ++t) {
    const char* Ab = lds + (t & 1) * LDS_TILE;
    const char* Bb = Ab + 32768;
    char* dN = lds + ((t & 1) ^ 1) * LDS_TILE;
    const int t1 = t + 1;
    // phase 1: quadrant (mh0, nh0); issue next A loads + 2 B stages
    LD_A(0); LD_B(0);
    A_ISSUE(t1);
    STG_B(0, t1, dN); STG_B(1, t1, dN);
    BAR; LGKM0; SCHB; PRIO(1); MM(0, 0); PRIO(0); SCHB; BAR;
    // phase 2: (mh0, nh1); 2 more B stages
    LD_B(1);
    STG_B(2, t1, dN); STG_B(3, t1, dN);
    BAR; LGKM0; SCHB; PRIO(1); MM(0, 1); PRIO(0); SCHB; BAR;
    // phase 3: (mh1, nh0); cvt rows 0-1 inside the MFMA region
    LD_A(1); LD_B(0);
    BAR; LGKM0; SCHB; PRIO(1);
    ACVT_ROW(dN, 0); ACVT_ROW(dN, 1);
    MM(1, 0);
    PRIO(0); SCHB; BAR;
    // phase 4: (mh1, nh1); cvt rows 2-3, then publish
    LD_B(1);
    BAR; LGKM0; SCHB; PRIO(1);
    ACVT_ROW(dN, 2); ACVT_ROW(dN, 3);
    MM(1, 1);
    PRIO(0); SCHB;
    VM(0);         // B gload_lds for t+1 complete
    LGKM0;         // my ds_writes visible before publish barrier
    BAR;
  }

  // ---- peeled last K-tile (no staging) ----
  {
    const char* Ab = lds + ((NT - 1) & 1) * LDS_TILE;
    const char* Bb = Ab + 32768;
    LD_A(0); LD_B(0);
    BAR; LGKM0; SCHB; PRIO(1); MM(0, 0); PRIO(0); SCHB; BAR;
    LD_B(1);
    BAR; LGKM0; SCHB; PRIO(1); MM(0, 1); PRIO(0); SCHB; BAR;
    LD_A(1); LD_B(0);
    BAR; LGKM0; SCHB; PRIO(1); MM(1, 0); PRIO(0); SCHB; BAR;
    LD_B(1);
    BAR; LGKM0; SCHB; PRIO(1); MM(1, 1); PRIO(0); SCHB;
  }

  // ---- epilogue: C/D layout col=l&15, row=(l>>4)*4+j; scale by dmod ----
  const int col0 = n0 + wc * 64 + l15;
  float dv[4];
#pragma unroll
  for (int nf = 0; nf < 4; ++nf) dv[nf] = dmod[b * 1024 + col0 + nf * 16];
#pragma unroll
  for (int mf = 0; mf < 8; ++mf) {
#pragma unroll
    for (int j = 0; j < 4; ++j) {
      const int row = m0 + wr * 128 + mf * 16 + lhi * 4 + j;
      float* orow = out + (size_t)row * 1024 + col0;
#pragma unroll
      for (int nf = 0; nf < 4; ++nf) orow[nf * 16] = acc[mf][nf][j] * dv[nf];
    }
  }
}

// ---------------------------------------------------------------------------
extern "C" void kernel_launch(void* const* d_in, const int* in_sizes, int n_in,
                              void* d_out, int out_size, void* d_ws, size_t ws_size,
                              hipStream_t stream) {
  const float* Efou = (const float*)d_in[0];  // 32*1024*1024 fp32
  const float* y    = (const float*)d_in[1];  // 32*1024 fp32
  const float* W    = (const float*)d_in[2];  // 1024*1024 fp32
  float* out = (float*)d_out;

  unsigned short* WT = (unsigned short*)d_ws;               // 2 MB bf16
  float* dpart       = (float*)(WT + (size_t)1024 * 1024);  // 4 MB fp32
  float* dmod        = dpart + (size_t)32 * 32768;          // 128 KB fp32

  hipFuncSetAttribute((const void*)gemmf5_kernel,
                      hipFuncAttributeMaxDynamicSharedMemorySize, 135168);

  prep_kernel<<<dim3(4, 32), 256, 0, stream>>>(y, W, dpart, WT);
  dcalc_b_kernel<<<128, 256, 0, stream>>>(dpart, dmod);
  gemmf5_kernel<<<512, 512, 135168, stream>>>(Efou, y, WT, dmod, out);
}